// Round 1
// baseline (772.742 us; speedup 1.0000x reference)
//
#include <hip/hip_runtime.h>
#include <math.h>

// Problem constants
#define NPOS   524288         // 8*16*64*64
#define KCODES 512
#define CDIM   64
#define THW    65536          // 16*64*64
#define MPOS   128            // positions per block
#define QCH    256            // codes per LDS chunk
#define EP     65             // padded e-row (dwords) -> conflict-free strided b32 reads
#define NTHREADS 256

// out layout (float32): [0, 33554432) quantized BCTHW; [33554432] loss; [33554433, +524288) indices
#define QOUT_N   33554432L
#define LOSS_OFF 33554432L
#define IDX_OFF  33554433L

// LDS (floats): a[64*128]=8192 | e[256*65]=16640 | ff[128] | ee[256] | idx[128]
// total 25344 floats = 101376 bytes (dynamic)

extern "C" __global__ __launch_bounds__(NTHREADS)
void vq_main(const float* __restrict__ x, const float* __restrict__ emb,
             float* __restrict__ out, double* __restrict__ lossws) {
    extern __shared__ float lds[];
    float* a   = lds;                    // [64][128]
    float* el  = lds + 8192;             // [QCH][EP]
    float* ffl = lds + 8192 + 16640;     // [128]
    float* eel = ffl + 128;              // [256]
    int*   idxl= (int*)(eel + 256);      // [128]

    const int tid = threadIdx.x;
    const int blk = blockIdx.x;
    const long n0 = (long)blk * MPOS;
    const int  b  = blk >> 9;                    // 512 blocks per batch element
    const long r0 = (long)(blk & 511) * MPOS;

    // ---- stage A-tile: a[c][p] = x[(b*64+c)*THW + r0 + p], coalesced float4
    {
        const float* xb = x + (long)b * 64 * THW + r0;
        #pragma unroll
        for (int k = 0; k < 8; ++k) {
            int f = tid + NTHREADS * k;          // 0..2047
            int c = f >> 5, col = (f & 31) * 4;
            float4 v = *(const float4*)(xb + (long)c * THW + col);
            *(float4*)(a + c * 128 + col) = v;
        }
    }
    __syncthreads();

    // ---- ff[p] = sum_c f_c^2 in numpy pairwise-8 order
    if (tid < 128) {
        float r[8];
        #pragma unroll
        for (int j = 0; j < 8; ++j) { float v = a[j * 128 + tid]; r[j] = __fmul_rn(v, v); }
        #pragma unroll
        for (int t = 1; t < 8; ++t) {
            #pragma unroll
            for (int j = 0; j < 8; ++j) {
                float v = a[(t * 8 + j) * 128 + tid];
                r[j] = __fadd_rn(r[j], __fmul_rn(v, v));
            }
        }
        float s0 = __fadd_rn(__fadd_rn(r[0], r[1]), __fadd_rn(r[2], r[3]));
        float s1 = __fadd_rn(__fadd_rn(r[4], r[5]), __fadd_rn(r[6], r[7]));
        ffl[tid] = __fadd_rn(s0, s1);
    }

    const int lane  = tid & 63;
    const int w     = tid >> 6;      // wave 0..3 -> positions [w*32, w*32+32)
    const int cg    = lane & 31;     // code group
    const int pg    = lane >> 5;     // pos group 0..1
    const int pbase = w * 32 + pg * 16;

    float dmin[16]; int kmin[16];
    #pragma unroll
    for (int j = 0; j < 16; ++j) { dmin[j] = 1e30f; kmin[j] = 0; }

    for (int ch = 0; ch < 2; ++ch) {
        __syncthreads();  // e_lds safe to overwrite (and ff ready before first use)
        // ---- stage E chunk: el[q][c] for q in [ch*256, ch*256+256)
        {
            const float* eb = emb + (long)ch * QCH * CDIM;
            #pragma unroll
            for (int k = 0; k < 16; ++k) {
                int f = tid + NTHREADS * k;      // 0..4095
                int q = f >> 4, c4 = (f & 15) * 4;
                float4 v = *(const float4*)(eb + q * 64 + c4);
                el[q * EP + c4 + 0] = v.x; el[q * EP + c4 + 1] = v.y;
                el[q * EP + c4 + 2] = v.z; el[q * EP + c4 + 3] = v.w;
            }
        }
        __syncthreads();
        // ---- ee[q] pairwise-8
        {
            int q = tid;
            float r[8];
            #pragma unroll
            for (int j = 0; j < 8; ++j) { float v = el[q * EP + j]; r[j] = __fmul_rn(v, v); }
            #pragma unroll
            for (int t = 1; t < 8; ++t) {
                #pragma unroll
                for (int j = 0; j < 8; ++j) {
                    float v = el[q * EP + t * 8 + j];
                    r[j] = __fadd_rn(r[j], __fmul_rn(v, v));
                }
            }
            float s0 = __fadd_rn(__fadd_rn(r[0], r[1]), __fadd_rn(r[2], r[3]));
            float s1 = __fadd_rn(__fadd_rn(r[4], r[5]), __fadd_rn(r[6], r[7]));
            eel[q] = __fadd_rn(s0, s1);
        }
        __syncthreads();

        // ---- dot: acc[j][i] = sum_c f[p_j,c]*e[q_i,c], sequential-c FMA chain
        float acc[16][8];
        #pragma unroll
        for (int j = 0; j < 16; ++j)
            #pragma unroll
            for (int i = 0; i < 8; ++i) acc[j][i] = 0.f;

        for (int c = 0; c < 64; ++c) {
            float ef[8];
            #pragma unroll
            for (int i = 0; i < 8; ++i) ef[i] = el[(cg + 32 * i) * EP + c];
            float af[16];
            #pragma unroll
            for (int j4 = 0; j4 < 4; ++j4) {
                float4 v = *(const float4*)(a + c * 128 + pbase + j4 * 4);
                af[j4*4+0] = v.x; af[j4*4+1] = v.y; af[j4*4+2] = v.z; af[j4*4+3] = v.w;
            }
            #pragma unroll
            for (int j = 0; j < 16; ++j)
                #pragma unroll
                for (int i = 0; i < 8; ++i)
                    acc[j][i] = __fmaf_rn(af[j], ef[i], acc[j][i]);
        }

        // ---- distances + running min (q ascending within thread)
        #pragma unroll
        for (int j = 0; j < 16; ++j) {
            float ffv = ffl[pbase + j];
            #pragma unroll
            for (int i = 0; i < 8; ++i) {
                int ql = cg + 32 * i;
                float d = __fsub_rn(__fadd_rn(ffv, eel[ql]), __fmul_rn(2.0f, acc[j][i]));
                int q = ch * QCH + ql;
                if (d < dmin[j]) { dmin[j] = d; kmin[j] = q; }
            }
        }
    }

    // ---- cross-lane argmin over the 32 code-groups (lowest-index tie-break)
    #pragma unroll
    for (int j = 0; j < 16; ++j) {
        #pragma unroll
        for (int m = 1; m <= 16; m <<= 1) {
            float od = __shfl_xor(dmin[j], m, 64);
            int   ok = __shfl_xor(kmin[j], m, 64);
            if (od < dmin[j] || (od == dmin[j] && ok < kmin[j])) { dmin[j] = od; kmin[j] = ok; }
        }
        if (cg == 0) idxl[pbase + j] = kmin[j];
    }
    __syncthreads();

    // ---- indices out (as float)
    if (tid < 128) out[IDX_OFF + n0 + tid] = (float)idxl[tid];

    // ---- quantized out (straight-through) + loss partial
    double lacc = 0.0;
    {
        float* ob = out + (long)b * 64 * THW + r0;
        #pragma unroll
        for (int k = 0; k < 8; ++k) {
            int f = tid + NTHREADS * k;          // 0..2047
            int c = f >> 5, col = (f & 31) * 4;
            float4 xv = *(const float4*)(a + c * 128 + col);
            float4 ov;
            {
                float q0 = emb[idxl[col + 0] * 64 + c];
                float d0 = __fsub_rn(q0, xv.x); ov.x = __fadd_rn(xv.x, d0);
                float s0 = __fmul_rn(d0, d0); lacc += (double)s0;
                float q1 = emb[idxl[col + 1] * 64 + c];
                float d1 = __fsub_rn(q1, xv.y); ov.y = __fadd_rn(xv.y, d1);
                float s1 = __fmul_rn(d1, d1); lacc += (double)s1;
                float q2 = emb[idxl[col + 2] * 64 + c];
                float d2 = __fsub_rn(q2, xv.z); ov.z = __fadd_rn(xv.z, d2);
                float s2 = __fmul_rn(d2, d2); lacc += (double)s2;
                float q3 = emb[idxl[col + 3] * 64 + c];
                float d3 = __fsub_rn(q3, xv.w); ov.w = __fadd_rn(xv.w, d3);
                float s3 = __fmul_rn(d3, d3); lacc += (double)s3;
            }
            *(float4*)(ob + (long)c * THW + col) = ov;
        }
    }
    // wave reduce then block reduce loss
    #pragma unroll
    for (int m = 1; m < 64; m <<= 1) lacc += __shfl_xor(lacc, m, 64);
    double* wsum = (double*)ffl;  // ff no longer needed; 8-byte aligned
    if (lane == 0) wsum[w] = lacc;
    __syncthreads();
    if (tid == 0) {
        double s = wsum[0] + wsum[1] + wsum[2] + wsum[3];
        atomicAdd(lossws, s);
    }
}

extern "C" __global__ void vq_finalize(const double* __restrict__ lossws,
                                       float* __restrict__ out) {
    if (threadIdx.x == 0) {
        float m = (float)(lossws[0] / (double)QOUT_N);  // /2^25 exact
        out[LOSS_OFF] = __fadd_rn(m, __fmul_rn(0.025f, m));
    }
}

extern "C" void kernel_launch(void* const* d_in, const int* in_sizes, int n_in,
                              void* d_out, int out_size, void* d_ws, size_t ws_size,
                              hipStream_t stream) {
    const float* x   = (const float*)d_in[0];
    const float* emb = (const float*)d_in[1];
    float* out = (float*)d_out;

    hipMemsetAsync(d_ws, 0, sizeof(double), stream);  // loss accumulator, zeroed every launch

    dim3 grid(NPOS / MPOS);   // 4096
    dim3 block(NTHREADS);
    size_t shmem = (8192 + 16640 + 128 + 256 + 128) * sizeof(float);  // 101376 B
    hipLaunchKernelGGL(vq_main, grid, block, shmem, stream, x, emb, out, (double*)d_ws);
    hipLaunchKernelGGL(vq_finalize, dim3(1), dim3(1), 0, stream,
                       (const double*)d_ws, out);
}